// Round 6
// baseline (301.882 us; speedup 1.0000x reference)
//
#include <hip/hip_runtime.h>
#include <hip/hip_bf16.h>

typedef __attribute__((ext_vector_type(8))) short short8;
typedef __attribute__((ext_vector_type(4))) float f32x4;
typedef unsigned short u16;
typedef unsigned int u32;

#define NBATCH 8
#define NA 1000
#define MD 64
#define GD 50
#define FD 128
#define TOTAL (NBATCH * NA)  // 8000

__device__ __forceinline__ u16 f2bf(float f) {
    u32 x = __float_as_uint(f);
    return (u16)((x + 0x7fffu + ((x >> 16) & 1u)) >> 16);  // RNE
}
__device__ __forceinline__ float bf2f(u16 u) {
    return __uint_as_float(((u32)u) << 16);
}
__device__ __forceinline__ u32 pkbf(float x, float y) {
    __hip_bfloat162 h = __float22bfloat162_rn(float2{x, y});
    return *reinterpret_cast<u32*>(&h);
}
__device__ __forceinline__ float tanh_fast(float x) {
    float e = __expf(2.0f * x);
    return 1.0f - 2.0f * __builtin_amdgcn_rcpf(e + 1.0f);
}
__device__ __forceinline__ f32x4 mfma16(short8 a, short8 b, f32x4 c) {
    return __builtin_amdgcn_mfma_f32_16x16x32_bf16(a, b, c, 0, 0, 0);
}

// ---------------- k0: fp32 weights -> bf16 transposed/padded panels ----------------
// W1T: [128 n][72 k], k<50 valid else 0.
// W2T/WiT/Wo1T/Wo2T: [2 p][128 n][72 kk], k=p*64+kk, kk<64 valid else 0.
__global__ void k0_prep(const float* __restrict__ W1, const float* __restrict__ W2,
                        const float* __restrict__ Wi, const float* __restrict__ Wo1,
                        const float* __restrict__ Wo2,
                        u16* __restrict__ W1T, u16* __restrict__ W2T,
                        u16* __restrict__ WiT, u16* __restrict__ Wo1T,
                        u16* __restrict__ Wo2T) {
    const int g0 = blockIdx.x * 256 + threadIdx.x;
    const int gstep = gridDim.x * 256;
    for (int i = g0; i < 128 * 72; i += gstep) {
        int n = i / 72, k = i - n * 72;
        int ks = (k < GD) ? k : 0;
        W1T[i] = (k < GD) ? f2bf(W1[ks * FD + n]) : (u16)0;
    }
    for (int i = g0; i < 2 * 128 * 72; i += gstep) {
        int p = i / 9216;
        int rem = i - p * 9216;
        int n = rem / 72, kk = rem - n * 72;
        bool valid = kk < 64;
        int k = p * 64 + (valid ? kk : 0);
        W2T[i]  = valid ? f2bf(W2[k * FD + n])  : (u16)0;
        WiT[i]  = valid ? f2bf(Wi[k * FD + n])  : (u16)0;
        Wo1T[i] = valid ? f2bf(Wo1[k * FD + n]) : (u16)0;
        Wo2T[i] = valid ? f2bf(Wo2[k * FD + n]) : (u16)0;
    }
}

// ---------------- k1: init = features @ W_init -> bf16 in ws ----------------
__global__ __launch_bounds__(256, 3) void k1_init(const float* __restrict__ feat,
                                                  const u16* __restrict__ WiT,
                                                  u16* __restrict__ initB) {
    __shared__ alignas(16) char smem[53248];
    u16* sA = (u16*)smem;              // [128][136] bf16
    u16* sW = (u16*)(smem + 34816);    // [128][72] panel
    const int tid = threadIdx.x, wid = tid >> 6, lane = tid & 63;
    const int quad = lane >> 4, col = lane & 15, rw = wid * 32;
    const int row0 = blockIdx.x * 128;

    for (int i = tid; i < 4096; i += 256) {
        int r = i >> 5, c = (i & 31) * 4;
        int gr = row0 + r;
        float4 v = {0.f, 0.f, 0.f, 0.f};
        if (gr < TOTAL) v = *(const float4*)&feat[(size_t)gr * FD + c];
        u32* p = (u32*)&sA[r * 136 + c];
        p[0] = pkbf(v.x, v.y);
        p[1] = pkbf(v.z, v.w);
    }
    for (int i = tid; i < 1152; i += 256) ((int4*)sW)[i] = ((const int4*)WiT)[i];
    __syncthreads();

    f32x4 acc[2][8];
    const f32x4 zf = {0.f, 0.f, 0.f, 0.f};
#pragma unroll
    for (int mt = 0; mt < 2; ++mt)
#pragma unroll
        for (int nt = 0; nt < 8; ++nt) acc[mt][nt] = zf;

    for (int half = 0; half < 2; ++half) {
        if (half) {
            __syncthreads();
            for (int i = tid; i < 1152; i += 256)
                ((int4*)sW)[i] = ((const int4*)(WiT + 9216))[i];
            __syncthreads();
        }
#pragma unroll
        for (int ks = 0; ks < 2; ++ks) {
            const int ka = half * 64 + ks * 32 + quad * 8;
            const int kb = ks * 32 + quad * 8;
            short8 a0 = *(const short8*)&sA[(rw + col) * 136 + ka];
            short8 a1 = *(const short8*)&sA[(rw + 16 + col) * 136 + ka];
#pragma unroll
            for (int nt = 0; nt < 8; ++nt) {
                short8 bfr = *(const short8*)&sW[(nt * 16 + col) * 72 + kb];
                acc[0][nt] = mfma16(a0, bfr, acc[0][nt]);
                acc[1][nt] = mfma16(a1, bfr, acc[1][nt]);
            }
        }
    }
#pragma unroll
    for (int mt = 0; mt < 2; ++mt)
#pragma unroll
        for (int nt = 0; nt < 8; ++nt)
#pragma unroll
            for (int r = 0; r < 4; ++r) {
                int row = rw + mt * 16 + quad * 4 + r;
                int gr = row0 + row;
                if (gr < TOTAL)
                    initB[(size_t)gr * FD + nt * 16 + col] = f2bf(acc[mt][nt][r]);
            }
}

// ---------------- k2: fused CFConv + attention, 2 atoms / block ----------------
// Waves split N: wave w owns n-tiles {2w, 2w+1} (cols [w*32, w*32+32)), all 128 rows.
// W1/W2 fragments live in registers. LDS 37,376 B -> 4 blocks/CU.
__global__ __launch_bounds__(256, 4) void k2_main(
    const float* __restrict__ rbf, const int* __restrict__ nl,
    const u16* __restrict__ initB,
    const u16* __restrict__ W1T, const u16* __restrict__ W2T,
    const float* __restrict__ b1, const float* __restrict__ b2,
    const float* __restrict__ nbrw,
    float* __restrict__ aggOut, float* __restrict__ attnO) {
    __shared__ alignas(16) char smem[37376];
    u16* sA = (u16*)smem;                    // rbf [128][72] -> H [128][136]
    int* nlS = (int*)(smem + 34816);         // [128]
    float* logitP = (float*)(smem + 35328);  // [4][128] per-wave logit partials
    float* attnS = (float*)smem;             // [128] aliases sA (H dead by use)

    const int tid = threadIdx.x, wid = tid >> 6, lane = tid & 63;
    const int quad = lane >> 4, col = lane & 15;
    const int nt0 = 2 * wid;  // this wave's n-tile base
    const int blk = blockIdx.x;
    const int b = blk / 500;
    const int n0 = (blk - b * 500) * 2;
    const int atom0 = b * NA + n0;
    const size_t rbf_base = (size_t)atom0 * (MD * GD);

    // ---- W1 fragments into registers (global, L2-hot) ----
    short8 w1f[2][2];  // [n][ks]
#pragma unroll
    for (int n = 0; n < 2; ++n)
#pragma unroll
        for (int ks = 0; ks < 2; ++ks)
            w1f[n][ks] = *(const short8*)&W1T[((nt0 + n) * 16 + col) * 72 +
                                              ks * 32 + quad * 8];
    float b1v[2];
#pragma unroll
    for (int n = 0; n < 2; ++n) b1v[n] = b1[(nt0 + n) * 16 + col];

    // ---- stage: nl + rbf(fp32->bf16) ----
    if (tid < 128) nlS[tid] = nl[atom0 * MD + tid];
    for (int i = tid; i < 128 * 14; i += 256) {  // zero pad k in [50,64)
        int r = i / 14;
        sA[r * 72 + 50 + (i - r * 14)] = 0;
    }
    for (int i = tid; i < 3200; i += 256) {
        int e = 2 * i;
        int r = e / 50, g = e - r * 50;
        float2 v = *(const float2*)&rbf[rbf_base + e];
        *(u32*)&sA[r * 72 + g] = pkbf(v.x, v.y);
    }
    __syncthreads();  // (1)

    // ---- layer 1: rbf @ W1 -> acc1[8 m][2 n] ----
    f32x4 acc1[8][2];
    const f32x4 zf = {0.f, 0.f, 0.f, 0.f};
#pragma unroll
    for (int m = 0; m < 8; ++m) {
        acc1[m][0] = zf;
        acc1[m][1] = zf;
    }
#pragma unroll
    for (int ks = 0; ks < 2; ++ks)
#pragma unroll
        for (int m = 0; m < 8; ++m) {
            short8 a = *(const short8*)&sA[(m * 16 + col) * 72 + ks * 32 + quad * 8];
            acc1[m][0] = mfma16(a, w1f[0][ks], acc1[m][0]);
            acc1[m][1] = mfma16(a, w1f[1][ks], acc1[m][1]);
        }
    __syncthreads();  // (2) all rbf reads done before H overwrite

    // ---- H = tanh(acc1+b1) -> sA [128][136] (this wave's 32-col slice) ----
#pragma unroll
    for (int m = 0; m < 8; ++m)
#pragma unroll
        for (int n = 0; n < 2; ++n)
#pragma unroll
            for (int r = 0; r < 4; ++r) {
                int row = m * 16 + quad * 4 + r;
                sA[row * 136 + (nt0 + n) * 16 + col] =
                    f2bf(tanh_fast(acc1[m][n][r] + b1v[n]));
            }
    // W2 fragments into registers while H settles
    short8 w2f[2][4];  // [n][kb], k = kb*32
#pragma unroll
    for (int n = 0; n < 2; ++n)
#pragma unroll
        for (int kb = 0; kb < 4; ++kb)
            w2f[n][kb] = *(const short8*)&W2T[(kb >> 1) * 9216 +
                                              ((nt0 + n) * 16 + col) * 72 +
                                              (kb & 1) * 32 + quad * 8];
    float b2v[2], wvv[2];
#pragma unroll
    for (int n = 0; n < 2; ++n) {
        b2v[n] = b2[(nt0 + n) * 16 + col];
        wvv[n] = nbrw[(nt0 + n) * 16 + col];
    }
    __syncthreads();  // (3)

    // ---- layer 2: H @ W2 -> acc2[8 m][2 n] ----
    f32x4 acc2[8][2];
#pragma unroll
    for (int m = 0; m < 8; ++m) {
        acc2[m][0] = zf;
        acc2[m][1] = zf;
    }
#pragma unroll
    for (int kb = 0; kb < 4; ++kb)
#pragma unroll
        for (int m = 0; m < 8; ++m) {
            short8 a = *(const short8*)&sA[(m * 16 + col) * 136 + kb * 32 + quad * 8];
            acc2[m][0] = mfma16(a, w2f[0][kb], acc2[m][0]);
            acc2[m][1] = mfma16(a, w2f[1][kb], acc2[m][1]);
        }

    // ---- conv + logit partials (this wave's 32 cols) ----
#pragma unroll
    for (int m = 0; m < 8; ++m)
#pragma unroll
        for (int r = 0; r < 4; ++r) {
            int row = m * 16 + quad * 4 + r;
            int ro = (b * NA + nlS[row]) * FD;
            float p = 0.f;
#pragma unroll
            for (int n = 0; n < 2; ++n) {
                float nb = bf2f(initB[ro + (nt0 + n) * 16 + col]);
                float cv = (acc2[m][n][r] + b2v[n]) * nb;
                acc2[m][n][r] = cv;  // conv stays in regs
                p += cv * wvv[n];
            }
#pragma unroll
            for (int d = 1; d < 16; d <<= 1) p += __shfl_xor(p, d, 64);
            if (col == 0) logitP[wid * 128 + row] = p;
        }
    __syncthreads();  // (4) also closes all layer-2 H reads -> attnS alias safe

    // ---- softmax over 64 neighbors per atom (waves 0,1) ----
    if (wid < 2) {
        int row = wid * 64 + lane;
        float x = logitP[row] + logitP[128 + row] + logitP[256 + row] +
                  logitP[384 + row];
        float mx = x;
#pragma unroll
        for (int d = 1; d < 64; d <<= 1) mx = fmaxf(mx, __shfl_xor(mx, d, 64));
        float e = __expf(x - mx);
        float s = e;
#pragma unroll
        for (int d = 1; d < 64; d <<= 1) s += __shfl_xor(s, d, 64);
        float a = e / s;
        attnS[row] = a;
        attnO[(size_t)(atom0 + wid) * MD + lane] = a;
    }
    __syncthreads();  // (5)

    // ---- agg: per-atom attn-weighted sum over rows, this wave's cols ----
    float aggp[2][2] = {{0.f, 0.f}, {0.f, 0.f}};  // [atom][n]
#pragma unroll
    for (int m = 0; m < 8; ++m) {
        int at = m >> 2;
#pragma unroll
        for (int r = 0; r < 4; ++r) {
            float a = attnS[m * 16 + quad * 4 + r];
            aggp[at][0] += a * acc2[m][0][r];
            aggp[at][1] += a * acc2[m][1][r];
        }
    }
#pragma unroll
    for (int d = 16; d < 64; d <<= 1)
#pragma unroll
        for (int at = 0; at < 2; ++at) {
            aggp[at][0] += __shfl_xor(aggp[at][0], d, 64);
            aggp[at][1] += __shfl_xor(aggp[at][1], d, 64);
        }
    if (quad == 0) {
#pragma unroll
        for (int at = 0; at < 2; ++at)
#pragma unroll
            for (int n = 0; n < 2; ++n)
                aggOut[(size_t)(atom0 + at) * FD + (nt0 + n) * 16 + col] =
                    aggp[at][n];
    }
}

// ---------------- k3: out = tanh(agg@Wo1+bo1)@Wo2+bo2, IN PLACE on d_out rows ----------------
__global__ __launch_bounds__(256, 3) void k3_out(
    float* __restrict__ outp, const u16* __restrict__ Wo1T,
    const u16* __restrict__ Wo2T, const float* __restrict__ bo1,
    const float* __restrict__ bo2) {
    __shared__ alignas(16) char smem[53248];
    u16* sA = (u16*)smem;            // [128][136]: agg rows, then t1
    u16* sW = (u16*)(smem + 34816);  // [128][72] panel
    const int tid = threadIdx.x, wid = tid >> 6, lane = tid & 63;
    const int quad = lane >> 4, col = lane & 15, rw = wid * 32;
    const int row0 = blockIdx.x * 128;

    for (int i = tid; i < 4096; i += 256) {
        int r = i >> 5, c = (i & 31) * 4;
        int gr = row0 + r;
        float4 v = {0.f, 0.f, 0.f, 0.f};
        if (gr < TOTAL) v = *(const float4*)&outp[(size_t)gr * FD + c];
        u32* p = (u32*)&sA[r * 136 + c];
        p[0] = pkbf(v.x, v.y);
        p[1] = pkbf(v.z, v.w);
    }
    for (int i = tid; i < 1152; i += 256) ((int4*)sW)[i] = ((const int4*)Wo1T)[i];
    __syncthreads();

    f32x4 acc[2][8];
    const f32x4 zf = {0.f, 0.f, 0.f, 0.f};
#pragma unroll
    for (int mt = 0; mt < 2; ++mt)
#pragma unroll
        for (int nt = 0; nt < 8; ++nt) acc[mt][nt] = zf;
    for (int half = 0; half < 2; ++half) {
        if (half) {
            __syncthreads();
            for (int i = tid; i < 1152; i += 256)
                ((int4*)sW)[i] = ((const int4*)(Wo1T + 9216))[i];
            __syncthreads();
        }
#pragma unroll
        for (int ks = 0; ks < 2; ++ks) {
            const int ka = half * 64 + ks * 32 + quad * 8;
            const int kb = ks * 32 + quad * 8;
            short8 a0 = *(const short8*)&sA[(rw + col) * 136 + ka];
            short8 a1 = *(const short8*)&sA[(rw + 16 + col) * 136 + ka];
#pragma unroll
            for (int nt = 0; nt < 8; ++nt) {
                short8 bfr = *(const short8*)&sW[(nt * 16 + col) * 72 + kb];
                acc[0][nt] = mfma16(a0, bfr, acc[0][nt]);
                acc[1][nt] = mfma16(a1, bfr, acc[1][nt]);
            }
        }
    }
    __syncthreads();

    float bias[8];
#pragma unroll
    for (int nt = 0; nt < 8; ++nt) bias[nt] = bo1[nt * 16 + col];
#pragma unroll
    for (int mt = 0; mt < 2; ++mt)
#pragma unroll
        for (int nt = 0; nt < 8; ++nt)
#pragma unroll
            for (int r = 0; r < 4; ++r) {
                int row = rw + mt * 16 + quad * 4 + r;
                sA[row * 136 + nt * 16 + col] =
                    f2bf(tanh_fast(acc[mt][nt][r] + bias[nt]));
            }
    for (int i = tid; i < 1152; i += 256) ((int4*)sW)[i] = ((const int4*)Wo2T)[i];
    __syncthreads();

    f32x4 acc2[2][8];
#pragma unroll
    for (int mt = 0; mt < 2; ++mt)
#pragma unroll
        for (int nt = 0; nt < 8; ++nt) acc2[mt][nt] = zf;
    for (int half = 0; half < 2; ++half) {
        if (half) {
            __syncthreads();
            for (int i = tid; i < 1152; i += 256)
                ((int4*)sW)[i] = ((const int4*)(Wo2T + 9216))[i];
            __syncthreads();
        }
#pragma unroll
        for (int ks = 0; ks < 2; ++ks) {
            const int ka = half * 64 + ks * 32 + quad * 8;
            const int kb = ks * 32 + quad * 8;
            short8 a0 = *(const short8*)&sA[(rw + col) * 136 + ka];
            short8 a1 = *(const short8*)&sA[(rw + 16 + col) * 136 + ka];
#pragma unroll
            for (int nt = 0; nt < 8; ++nt) {
                short8 bfr = *(const short8*)&sW[(nt * 16 + col) * 72 + kb];
                acc2[0][nt] = mfma16(a0, bfr, acc2[0][nt]);
                acc2[1][nt] = mfma16(a1, bfr, acc2[1][nt]);
            }
        }
    }
#pragma unroll
    for (int nt = 0; nt < 8; ++nt) bias[nt] = bo2[nt * 16 + col];
#pragma unroll
    for (int mt = 0; mt < 2; ++mt)
#pragma unroll
        for (int nt = 0; nt < 8; ++nt)
#pragma unroll
            for (int r = 0; r < 4; ++r) {
                int row = rw + mt * 16 + quad * 4 + r;
                int gr = row0 + row;
                if (gr < TOTAL)
                    outp[(size_t)gr * FD + nt * 16 + col] =
                        acc2[mt][nt][r] + bias[nt];
            }
}

extern "C" void kernel_launch(void* const* d_in, const int* in_sizes, int n_in,
                              void* d_out, int out_size, void* d_ws,
                              size_t ws_size, hipStream_t stream) {
    const float* feat = (const float*)d_in[0];
    const float* rbf  = (const float*)d_in[1];
    const int*   nl   = (const int*)d_in[2];
    const float* Wi   = (const float*)d_in[3];
    const float* W1   = (const float*)d_in[4];
    const float* b1   = (const float*)d_in[5];
    const float* W2   = (const float*)d_in[6];
    const float* b2   = (const float*)d_in[7];
    const float* nbrw = (const float*)d_in[8];
    const float* Wo1  = (const float*)d_in[9];
    const float* bo1  = (const float*)d_in[10];
    const float* Wo2  = (const float*)d_in[11];
    const float* bo2  = (const float*)d_in[12];

    float* outp  = (float*)d_out;               // [8000][128] (agg scratch, then final)
    float* attnp = outp + (size_t)TOTAL * FD;   // [8000][64]

    char* ws = (char*)d_ws;                     // total use: 2,213,888 B
    u16* initB = (u16*)ws;                      // 2,048,000 B
    u16* W1T   = (u16*)(ws + 2048000);          // 18,432 B
    u16* W2T   = (u16*)(ws + 2048000 + 18432);  // 36,864 B
    u16* WiT   = (u16*)(ws + 2048000 + 18432 + 36864);
    u16* Wo1T  = (u16*)(ws + 2048000 + 18432 + 2 * 36864);
    u16* Wo2T  = (u16*)(ws + 2048000 + 18432 + 3 * 36864);

    hipLaunchKernelGGL(k0_prep, dim3(40), dim3(256), 0, stream,
                       W1, W2, Wi, Wo1, Wo2, W1T, W2T, WiT, Wo1T, Wo2T);
    hipLaunchKernelGGL(k1_init, dim3(63), dim3(256), 0, stream, feat, WiT, initB);
    hipLaunchKernelGGL(k2_main, dim3(4000), dim3(256), 0, stream,
                       rbf, nl, initB, W1T, W2T, b1, b2, nbrw, outp, attnp);
    hipLaunchKernelGGL(k3_out, dim3(63), dim3(256), 0, stream,
                       outp, Wo1T, Wo2T, bo1, bo2);
}